// Round 8
// baseline (676.257 us; speedup 1.0000x reference)
//
#include <hip/hip_runtime.h>
#include <stdint.h>

#define TILES 8
#define HH 4096
#define WW 4096
#define CC 3
#define TH 512
#define TW 512
#define AREA (TH * TW)
#define CLIPV 1228u   // int(1.2 * 262144 / 256)
#define NTILE (CC * TILES * TILES)   // 192

typedef float f4 __attribute__((ext_vector_type(4)));
typedef float f2 __attribute__((ext_vector_type(2)));

// ---------------------------------------------------------------------------
// Pass 1: per-tile partial histograms + cache quantized v bytes + FOLDED LUT.
// grid = 192 tiles * 16 sub-slabs = 3072 blocks, 256 threads.
// nt hints restored (round-6 ablation: removing them cost +50us -- plain
// streaming pollutes L2/LLC and evicts vpack between passes).
// After writing its partial, each block bumps a device-scope per-tile
// counter; the 16th (last) arriver computes that tile's LUT in-place with
// the byte-identical clip/redistribute/scan math. Saves one dispatch.
// ---------------------------------------------------------------------------
__global__ __launch_bounds__(256) void clahe_hist_kernel(
    const float* __restrict__ img,
    uint32_t* __restrict__ vpack,        // packed v bytes (4 per uint)
    int store_v,
    uint32_t* __restrict__ hist_part,    // [3072][256]
    float* __restrict__ lut,             // [192][256]
    uint32_t* __restrict__ tile_cnt)     // [192], zeroed by memsetAsync per launch
{
    __shared__ uint32_t sh[4 * 264];   // 4 per-wave sub-hists; reused in LUT tail
    __shared__ uint32_t is_last;

    const int tid  = threadIdx.x;
    const int wave = tid >> 6;
    const int lane = tid & 63;
    uint32_t* myh  = sh + wave * 264;

    for (int i = tid; i < 4 * 264; i += 256) sh[i] = 0;
    __syncthreads();

    const int bid = blockIdx.x;
    const int sub = bid & 15;       // which 32-row slab of the tile
    const int tl  = bid >> 4;       // c*64 + ty*8 + tx
    const int tx  = tl & 7;
    const int ty  = (tl >> 3) & 7;
    const int c   = tl >> 6;

    const size_t base4 = ((size_t)c * HH + (size_t)(ty * TH + sub * 32)) * (WW / 4)
                       + (size_t)tx * (TW / 4);
    const f4* img4 = (const f4*)img;

    for (int it = 0; it < 4; ++it) {
        const int i0 = it * 1024 + tid;
        size_t addr[4];
        f4 p[4];
#pragma unroll
        for (int j = 0; j < 4; ++j) {
            const int s  = i0 + j * 256;       // [0,4096) float4 slot
            const int rl = s >> 7;             // 128 float4 per 512-wide row
            const int c4 = s & 127;
            addr[j] = base4 + (size_t)rl * (WW / 4) + (size_t)c4;
            p[j] = __builtin_nontemporal_load(&img4[addr[j]]);   // nt restored
        }
#pragma unroll
        for (int j = 0; j < 4; ++j) {
            int v0 = min(max((int)(p[j][0] * 255.0f), 0), 255);
            int v1 = min(max((int)(p[j][1] * 255.0f), 0), 255);
            int v2 = min(max((int)(p[j][2] * 255.0f), 0), 255);
            int v3 = min(max((int)(p[j][3] * 255.0f), 0), 255);

            atomicAdd(&myh[v0], 1u);
            atomicAdd(&myh[v1], 1u);
            atomicAdd(&myh[v2], 1u);
            atomicAdd(&myh[v3], 1u);

            if (store_v) {
                uint32_t pk = (uint32_t)v0 | ((uint32_t)v1 << 8) |
                              ((uint32_t)v2 << 16) | ((uint32_t)v3 << 24);
                vpack[addr[j]] = pk;           // normal store: want LLC residency
            }
        }
    }
    __syncthreads();

    const uint32_t ps = sh[tid] + sh[264 + tid] + sh[528 + tid] + sh[792 + tid];
    hist_part[(size_t)bid * 256 + tid] = ps;

    // ---- last-arriver-per-tile computes the LUT (no grid sync needed) ----
    if (tid == 0) {
        __threadfence();   // release: partial visible device-wide before arrive
        const uint32_t prev = __hip_atomic_fetch_add(
            &tile_cnt[tl], 1u, __ATOMIC_ACQ_REL, __HIP_MEMORY_SCOPE_AGENT);
        is_last = (prev == 15u) ? 1u : 0u;
    }
    __syncthreads();
    if (!is_last) return;
    __threadfence();       // acquire: drop stale cached lines before peer reads

    const uint32_t* hp = hist_part + (size_t)tl * 16 * 256;
    uint32_t h = 0;
#pragma unroll
    for (int s = 0; s < 16; ++s) h += hp[s * 256 + tid];

    const uint32_t cl = min(h, CLIPV);
    uint32_t ex = h - cl;
#pragma unroll
    for (int d = 32; d > 0; d >>= 1) ex += __shfl_down(ex, d, 64);
    __syncthreads();                     // sh reuse: everyone past partial reads
    uint32_t* exs = sh;
    float* wsum = (float*)(sh + 8);
    if (lane == 0) exs[wave] = ex;
    __syncthreads();
    const uint32_t extot = exs[0] + exs[1] + exs[2] + exs[3];

    float x = (float)cl + (float)extot * (1.0f / 256.0f);
#pragma unroll
    for (int d = 1; d < 64; d <<= 1) {
        float t = __shfl_up(x, d, 64);
        if (lane >= d) x += t;
    }
    if (lane == 63) wsum[wave] = x;
    __syncthreads();
    float add = 0.0f;
    for (int w = 0; w < wave; ++w) add += wsum[w];
    const float cdf = x + add;

    float l = rintf(cdf * (255.0f / (float)AREA));   // RNE == jnp.round
    l = fminf(fmaxf(l, 0.0f), 255.0f);
    lut[(size_t)tl * 256 + tid] = l;
}

// ---------------------------------------------------------------------------
// Pass 2: slab-based apply (round-5 structure, nt hints restored).
// One block per 64-row x 512-col slab (grid = 1536). y0/y1 block constants;
// x0/x1 thread constants. LDS: 4 interleaved pair-tables, one ds_read_b64
// fetches both bilinear x-neighbors.
// ---------------------------------------------------------------------------
__global__ __launch_bounds__(256) void clahe_apply_kernel(
    const float* __restrict__ img,
    const uint32_t* __restrict__ vpack,
    const float* __restrict__ lut,
    float* __restrict__ out,
    int use_v)
{
    __shared__ float Lh[4 * 512];   // 8 KB

    const int tid = threadIdx.x;
    const int bid = blockIdx.x;
    const int sub = bid & 7;        // which 64-row slab of the tile
    const int tl  = bid >> 3;       // c*64 + ty*8 + tx
    const int tx  = tl & 7;
    const int ty  = (tl >> 3) & 7;
    const int c   = tl >> 6;

    const int row0 = ty * TH + sub * 64;
    const size_t base4 = ((size_t)c * HH + (size_t)row0) * (WW / 4) + (size_t)tx * (TW / 4);

    // ---- block-constant interp geometry ----
    const int y0 = (sub < 4) ? max(ty - 1, 0) : ty;   // boundary at tile row 256
    const int y1 = min(y0 + 1, TILES - 1);
    const int xl = max(tx - 1, 0);
    const int xr = min(tx + 1, TILES - 1);

    // ---- fill the 4 interleaved pair-tables (2048 floats, 8 per thread) ----
#pragma unroll
    for (int t = 0; t < 8; ++t) {
        const int e   = t * 256 + tid;
        const int arr = e >> 9;         // 0..3
        const int i   = e & 511;
        const int v   = i >> 1;
        const int w   = i & 1;
        const int ys  = (arr & 2) ? y1 : y0;
        const int xs  = (arr & 1) ? (w ? xr : tx) : (w ? tx : xl);
        Lh[e] = lut[((size_t)(c * TILES + ys) * TILES + xs) * 256 + v];
    }
    __syncthreads();

    // ---- thread-constant x geometry ----
    const int c4 = tid & 127;                          // thread's fixed f4 column
    const float fx0 = ((float)(tx * TW + c4 * 4) + 0.5f) * (1.0f / (float)TW) - 0.5f;
    int x0i = (int)floorf(fx0);
    x0i = min(max(x0i, 0), TILES - 1);
    const float fxr = fx0 - (float)x0i;
    float ax[4];
#pragma unroll
    for (int k = 0; k < 4; ++k)
        ax[k] = fminf(fmaxf(fxr + (float)k * (1.0f / (float)TW), 0.0f), 1.0f);

    const int x0k = (c4 < 64) ? 0 : 1;                 // left half -> (xl,tx), right -> (tx,xr)
    const float* topA = Lh + x0k * 512;                // y0 pair table
    const float* botA = Lh + 1024 + x0k * 512;         // y1 pair table
    const float y0f = (float)y0;

    const f4* img4 = (const f4*)img;
    f4* out4 = (f4*)out;

    // ---- stream 32 f4/thread in chunks of 8 (loads prefetched per chunk) ----
    for (int it8 = 0; it8 < 4; ++it8) {
        uint32_t pv[8];
        f4 p[8];
        int rls[8];
        size_t off[8];
#pragma unroll
        for (int j = 0; j < 8; ++j) {
            const int s = (it8 * 8 + j) * 256 + tid;   // [0,8192) f4 slot in slab
            const int rl = s >> 7;                     // row within slab (0..63)
            rls[j] = rl;
            off[j] = (size_t)rl * (WW / 4) + (size_t)c4;
            if (use_v) pv[j] = vpack[base4 + off[j]];
            else       p[j]  = __builtin_nontemporal_load(&img4[base4 + off[j]]);
        }
#pragma unroll
        for (int j = 0; j < 8; ++j) {
            const float fy = ((float)(row0 + rls[j]) + 0.5f) * (1.0f / (float)TH) - 0.5f;
            const float ay = fminf(fmaxf(fy - y0f, 0.0f), 1.0f);
            float res[4];
#pragma unroll
            for (int k = 0; k < 4; ++k) {
                int v;
                if (use_v) v = (int)((pv[j] >> (8 * k)) & 255u);
                else       v = min(max((int)(p[j][k] * 255.0f), 0), 255);
                const f2 tpr = *(const f2*)&topA[v * 2];   // ds_read_b64: (g00,g01)
                const f2 bpr = *(const f2*)&botA[v * 2];   // ds_read_b64: (g10,g11)
                const float top = tpr[0] + ax[k] * (tpr[1] - tpr[0]);
                const float bot = bpr[0] + ax[k] * (bpr[1] - bpr[0]);
                res[k] = (top + ay * (bot - top)) * (1.0f / 255.0f);
            }
            f4 o = { res[0], res[1], res[2], res[3] };
            __builtin_nontemporal_store(o, &out4[base4 + off[j]]);  // nt restored
        }
    }
}

// ---------------------------------------------------------------------------
extern "C" void kernel_launch(void* const* d_in, const int* in_sizes, int n_in,
                              void* d_out, int out_size, void* d_ws, size_t ws_size,
                              hipStream_t stream)
{
    const float* img = (const float*)d_in[0];
    float* out = (float*)d_out;

    uint8_t* ws = (uint8_t*)d_ws;
    float*    lut       = (float*)ws;                      // 192*256*4   = 196608 B
    uint32_t* hist_part = (uint32_t*)(ws + 196608);        // 3072*256*4  = 3145728 B
    uint32_t* tile_cnt  = (uint32_t*)(ws + 196608 + 3145728);        // 192*4, pad 4096
    uint32_t* vpack     = (uint32_t*)(ws + 196608 + 3145728 + 4096); // 48 MB packed v

    const size_t need_v = 196608 + 3145728 + 4096 + (size_t)CC * HH * WW;
    const int use_v = (ws_size >= need_v) ? 1 : 0;

    // zero the per-tile arrival counters (workspace is re-poisoned by the
    // harness; stream memset is graph-capturable -- harness uses it itself)
    hipMemsetAsync(tile_cnt, 0, NTILE * sizeof(uint32_t), stream);

    clahe_hist_kernel<<<CC * 64 * 16, 256, 0, stream>>>(img, vpack, use_v,
                                                        hist_part, lut, tile_cnt);
    clahe_apply_kernel<<<CC * TILES * TILES * 8, 256, 0, stream>>>(img, vpack, lut, out, use_v);
}

// Round 9
// 335.344 us; speedup vs baseline: 2.0166x; 2.0166x over previous
//
#include <hip/hip_runtime.h>
#include <stdint.h>

#define TILES 8
#define HH 4096
#define WW 4096
#define CC 3
#define TH 512
#define TW 512
#define AREA (TH * TW)
#define CLIPV 1228u   // int(1.2 * 262144 / 256)

typedef float f4 __attribute__((ext_vector_type(4)));

// ---------------------------------------------------------------------------
// Pass 1: per-tile partial histograms + cache quantized v bytes.
// grid = 192 tiles * 16 sub-slabs = 3072 blocks, 256 threads.
// Each block: 32 rows x 512 cols of one tile. Nontemporal img loads (no
// reuse; round-6 ablation proved removing nt costs +50us). Each block writes
// its own hist_part[bid][256] -- no global atomics, no zero-init, and NO
// device-scope fences (round-8 ablation: per-block threadfence+atomic for a
// folded LUT cost +330us -- fences after 48MB of nt stores drain the pipe).
// ---------------------------------------------------------------------------
__global__ __launch_bounds__(256) void clahe_hist_kernel(
    const float* __restrict__ img,
    uint32_t* __restrict__ vpack,        // packed v bytes (4 per uint)
    int store_v,
    uint32_t* __restrict__ hist_part)    // [3072][256]
{
    __shared__ uint32_t sh[4 * 264];   // 4 per-wave sub-hists
    const int tid  = threadIdx.x;
    const int wave = tid >> 6;
    uint32_t* myh  = sh + wave * 264;

    for (int i = tid; i < 4 * 264; i += 256) sh[i] = 0;
    __syncthreads();

    const int bid = blockIdx.x;
    const int sub = bid & 15;       // which 32-row slab of the tile
    const int tl  = bid >> 4;       // c*64 + ty*8 + tx
    const int tx  = tl & 7;
    const int ty  = (tl >> 3) & 7;
    const int c   = tl >> 6;

    // base in float4 units
    const size_t base4 = ((size_t)c * HH + (size_t)(ty * TH + sub * 32)) * (WW / 4)
                       + (size_t)tx * (TW / 4);
    const f4* img4 = (const f4*)img;

    for (int it = 0; it < 4; ++it) {
        const int i0 = it * 1024 + tid;
        size_t addr[4];
        f4 p[4];
#pragma unroll
        for (int j = 0; j < 4; ++j) {
            const int s  = i0 + j * 256;       // [0,4096) float4 slot
            const int rl = s >> 7;             // 128 float4 per 512-wide row
            const int c4 = s & 127;
            addr[j] = base4 + (size_t)rl * (WW / 4) + (size_t)c4;
            p[j] = __builtin_nontemporal_load(&img4[addr[j]]);  // 4 loads in flight
        }
#pragma unroll
        for (int j = 0; j < 4; ++j) {
            int v0 = min(max((int)(p[j][0] * 255.0f), 0), 255);
            int v1 = min(max((int)(p[j][1] * 255.0f), 0), 255);
            int v2 = min(max((int)(p[j][2] * 255.0f), 0), 255);
            int v3 = min(max((int)(p[j][3] * 255.0f), 0), 255);

            atomicAdd(&myh[v0], 1u);
            atomicAdd(&myh[v1], 1u);
            atomicAdd(&myh[v2], 1u);
            atomicAdd(&myh[v3], 1u);

            if (store_v) {
                uint32_t pk = (uint32_t)v0 | ((uint32_t)v1 << 8) |
                              ((uint32_t)v2 << 16) | ((uint32_t)v3 << 24);
                vpack[addr[j]] = pk;           // normal store: want LLC residency
            }
        }
    }
    __syncthreads();

    const uint32_t s = sh[tid] + sh[264 + tid] + sh[528 + tid] + sh[792 + tid];
    hist_part[(size_t)bid * 256 + tid] = s;    // plain coalesced store
}

// ---------------------------------------------------------------------------
// Pass 2: sum 16 partials, clip + redistribute + scan -> LUT.
// grid = C*64 blocks, 256 threads.
// ---------------------------------------------------------------------------
__global__ __launch_bounds__(256) void clahe_lut_kernel(
    const uint32_t* __restrict__ hist_part,
    float* __restrict__ lut)
{
    __shared__ uint32_t exs[4];
    __shared__ float wsum[4];

    const int tid  = threadIdx.x;
    const int wave = tid >> 6;
    const int lane = tid & 63;
    const int blk  = blockIdx.x;

    const uint32_t* hp = hist_part + (size_t)blk * 16 * 256;
    uint32_t h = 0;
#pragma unroll
    for (int s = 0; s < 16; ++s) h += hp[s * 256 + tid];

    const uint32_t cl = min(h, CLIPV);
    uint32_t ex = h - cl;

#pragma unroll
    for (int d = 32; d > 0; d >>= 1) ex += __shfl_down(ex, d, 64);
    if (lane == 0) exs[wave] = ex;
    __syncthreads();
    const uint32_t extot = exs[0] + exs[1] + exs[2] + exs[3];

    float x = (float)cl + (float)extot * (1.0f / 256.0f);

#pragma unroll
    for (int d = 1; d < 64; d <<= 1) {
        float t = __shfl_up(x, d, 64);
        if (lane >= d) x += t;
    }
    if (lane == 63) wsum[wave] = x;
    __syncthreads();
    float add = 0.0f;
    for (int w = 0; w < wave; ++w) add += wsum[w];
    const float cdf = x + add;

    float l = rintf(cdf * (255.0f / (float)AREA));   // RNE == jnp.round
    l = fminf(fmaxf(l, 0.0f), 255.0f);
    lut[(size_t)blk * 256 + tid] = l;
}

// ---------------------------------------------------------------------------
// Pass 3: one block per image row. Prefetch the row's pixel data FIRST (loads
// stay in flight across the barrier), y-blend the two tile-row LUTs into LDS,
// then 2 LDS gathers per pixel. Single barrier; out stores at block end via
// nontemporal (out is never re-read). grid = C*H = 12288 blocks.
// ---------------------------------------------------------------------------
__global__ __launch_bounds__(256) void clahe_apply_kernel(
    const float* __restrict__ img,
    const uint32_t* __restrict__ vpack,
    const float* __restrict__ lut,
    float* __restrict__ out,
    int use_v)
{
    __shared__ float rb[TILES * 256];   // y-blended LUT for this row: [x][v]

    const int tid = threadIdx.x;
    const int b = blockIdx.x;
    const int y = b & (HH - 1);
    const int c = b >> 12;

    const size_t rowbase4 = ((size_t)c * HH + (size_t)y) * (WW / 4);
    const f4* img4 = (const f4*)img;

    // ---- prefetch pixel data for all 4 slots (in flight during rb fill) ----
    uint32_t pv[4];
    f4 p[4];
    if (use_v) {
#pragma unroll
        for (int s = 0; s < 4; ++s) pv[s] = vpack[rowbase4 + s * 256 + tid];
    } else {
#pragma unroll
        for (int s = 0; s < 4; ++s) p[s] = img4[rowbase4 + s * 256 + tid];
    }

    // ---- rb fill ----
    const float fy = ((float)y + 0.5f) * (1.0f / (float)TH) - 0.5f;
    int y0 = (int)floorf(fy);
    y0 = min(max(y0, 0), TILES - 1);
    const float ay = fminf(fmaxf(fy - (float)y0, 0.0f), 1.0f);
    const int y1 = min(y0 + 1, TILES - 1);

    const float* lr0 = lut + ((size_t)(c * TILES + y0) * TILES) * 256;
    const float* lr1 = lut + ((size_t)(c * TILES + y1) * TILES) * 256;

#pragma unroll
    for (int k = 0; k < 8; ++k) {
        const int i = k * 256 + tid;
        const float a = lr0[i];
        const float d = lr1[i];
        rb[i] = a + ay * (d - a);
    }
    __syncthreads();

#pragma unroll
    for (int s = 0; s < 4; ++s) {
        const int slot = s * 256 + tid;       // [0,1024) float4 in row

        // all 4 pixels of an aligned float4 share x0/x1 (boundary at 255.5+512n)
        const int xbase = slot * 4;
        const float fx0 = ((float)xbase + 0.5f) * (1.0f / (float)TW) - 0.5f;
        int x0 = (int)floorf(fx0);
        x0 = min(max(x0, 0), TILES - 1);
        const int x1 = min(x0 + 1, TILES - 1);
        const float* r0 = rb + x0 * 256;
        const float* r1 = rb + x1 * 256;
        const float fxr = fx0 - (float)x0;

        float res[4];
#pragma unroll
        for (int k = 0; k < 4; ++k) {
            int v;
            if (use_v) {
                v = (int)((pv[s] >> (8 * k)) & 255u);
            } else {
                v = min(max((int)(p[s][k] * 255.0f), 0), 255);
            }
            const float ax = fminf(fmaxf(fxr + (float)k * (1.0f / (float)TW), 0.0f), 1.0f);
            const float g0 = r0[v];
            const float g1 = r1[v];
            res[k] = (g0 + ax * (g1 - g0)) * (1.0f / 255.0f);
        }
        f4 o4 = { res[0], res[1], res[2], res[3] };
        __builtin_nontemporal_store(o4, ((f4*)out) + rowbase4 + slot);
    }
}

// ---------------------------------------------------------------------------
extern "C" void kernel_launch(void* const* d_in, const int* in_sizes, int n_in,
                              void* d_out, int out_size, void* d_ws, size_t ws_size,
                              hipStream_t stream)
{
    const float* img = (const float*)d_in[0];
    float* out = (float*)d_out;

    uint8_t* ws = (uint8_t*)d_ws;
    float*    lut       = (float*)ws;                     // 3*64*256 f32 = 196608 B
    uint32_t* hist_part = (uint32_t*)(ws + 196608);       // 3072*256 u32 = 3145728 B
    uint32_t* vpack     = (uint32_t*)(ws + 196608 + 3145728);  // 48 MB packed v

    const size_t need_v = 196608 + 3145728 + (size_t)CC * HH * WW;
    const int use_v = (ws_size >= need_v) ? 1 : 0;

    clahe_hist_kernel<<<CC * 64 * 16, 256, 0, stream>>>(img, vpack, use_v, hist_part);
    clahe_lut_kernel<<<CC * 64, 256, 0, stream>>>(hist_part, lut);
    clahe_apply_kernel<<<CC * HH, 256, 0, stream>>>(img, vpack, lut, out, use_v);
}